// Round 2
// baseline (773.535 us; speedup 1.0000x reference)
//
#include <hip/hip_runtime.h>
#include <math.h>

#define AFWD 0.999f
#define EPS  1e-5f

constexpr int B      = 32;
constexpr int HW     = 64 * 64;      // 4096 spatial positions per sample
constexpr int C      = 256;          // channels
constexpr int CQ     = C / 4;        // 64 float4 per spatial row
constexpr int R      = 64;           // rows per chunk (64 KB of data per block-iteration)
constexpr int CHUNKS = HW / R;       // 64 chunks per sample
constexpr int TG     = 8;            // t-groups concurrently in flight
constexpr int GRID   = TG * CHUNKS;  // 512 blocks = 2 per CU on 256 CUs
constexpr int ITERS  = B / TG;       // 4 (t,chunk) pairs per block
constexpr int F4PT   = R / 4;        // 16 float4 held per thread

// Native vector type for __builtin_nontemporal_store (HIP's float4 is a class).
typedef float nfloat4 __attribute__((ext_vector_type(4)));

// ---------------------------------------------------------------------------
// One-pass fused Online-Norm forward.
//   Block b: t-group tg = b>>6, chunk = b&63. Iteration i handles t = i*8+tg.
//   Per iteration: load chunk -> regs (read x ONCE), partial sums -> atomicAdd
//   accum[t], release-publish done[t]; spin (thread 0) until done[tt]==CHUNKS
//   for all tt < t; incremental EMA carry scan; normalize the register-held
//   chunk and NT-store out (never re-read -> keep out of L2/L3).
//   Deadlock-free under co-residency (cooperative launch): every block
//   publishes its sums before waiting, and waits only on strictly smaller t.
// ---------------------------------------------------------------------------
__global__ void __launch_bounds__(256, 2)
fused_onorm(const float4* __restrict__ x4,
            const float*  __restrict__ mu0,
            const float*  __restrict__ var0,
            float*        __restrict__ accum_s,
            float*        __restrict__ accum_q,
            int*          __restrict__ done,
            float4*       __restrict__ out4) {
    const int b     = blockIdx.x;
    const int tg    = b >> 6;        // [0,8)
    const int chunk = b & 63;        // [0,64)
    const int tid   = threadIdx.x;
    const int cq    = tid & 63;      // channel quad
    const int rs    = tid >> 6;      // row sub-lane

    __shared__ float4 ls[256];                    // 4 KB
    __shared__ float4 lq[256];                    // 4 KB
    __shared__ __align__(16) float smu[C];        // 1 KB
    __shared__ __align__(16) float srs[C];        // 1 KB

    // Per-thread EMA carry for channel c = tid, scanned through [0, upto).
    float mu  = mu0[tid];
    float var = var0[tid];
    int upto  = 0;
    const float inv = 1.0f / (float)HW;

    for (int i = 0; i < ITERS; ++i) {
        const int t    = i * TG + tg;
        const int base = (t * HW + chunk * R) * CQ;   // fits in int (134 MB / 16 B)

        // ---- Phase 1: load chunk into registers (coalesced: wave = 1 KB/instr)
        float4 v[F4PT];
        #pragma unroll
        for (int k = 0; k < F4PT; ++k)
            v[k] = x4[base + (rs + k * 4) * CQ + cq];

        // ---- Phase 2: per-thread partial sums
        float4 s = make_float4(0.f, 0.f, 0.f, 0.f);
        float4 q = make_float4(0.f, 0.f, 0.f, 0.f);
        #pragma unroll
        for (int k = 0; k < F4PT; ++k) {
            s.x += v[k].x; s.y += v[k].y; s.z += v[k].z; s.w += v[k].w;
            q.x += v[k].x * v[k].x; q.y += v[k].y * v[k].y;
            q.z += v[k].z * v[k].z; q.w += v[k].w * v[k].w;
        }

        ls[tid] = s;
        lq[tid] = q;
        __syncthreads();                                   // A: ls/lq ready
        {
            // Thread tid owns channel c = tid; word index k*256+c -> bank c%32,
            // conflict-free.
            const int c2 = tid >> 2, comp = tid & 3;
            float ss = 0.f, qq = 0.f;
            #pragma unroll
            for (int k = 0; k < 4; ++k) {
                ss += ((const float*)&ls[k * 64 + c2])[comp];
                qq += ((const float*)&lq[k * 64 + c2])[comp];
            }
            atomicAdd(&accum_s[t * C + tid], ss);
            atomicAdd(&accum_q[t * C + tid], qq);
        }
        __threadfence();                                   // order adds to agent scope
        __syncthreads();                                   // B: all adds drained

        if (tid == 0) {
            __hip_atomic_fetch_add(&done[t], 1, __ATOMIC_RELEASE,
                                   __HIP_MEMORY_SCOPE_AGENT);
            // Wait for every sample < t to be fully accumulated (monotonic).
            for (int tt = upto; tt < t; ++tt)
                while (__hip_atomic_load(&done[tt], __ATOMIC_ACQUIRE,
                                         __HIP_MEMORY_SCOPE_AGENT) < CHUNKS)
                    __builtin_amdgcn_s_sleep(2);
        }
        __syncthreads();                                   // C: deps satisfied

        // ---- Phase 3: incremental EMA carry scan for channel c = tid
        for (int tt = upto; tt < t; ++tt) {
            const float S = __hip_atomic_load(&accum_s[tt * C + tid],
                                              __ATOMIC_RELAXED,
                                              __HIP_MEMORY_SCOPE_AGENT);
            const float Q = __hip_atomic_load(&accum_q[tt * C + tid],
                                              __ATOMIC_RELAXED,
                                              __HIP_MEMORY_SCOPE_AGENT);
            const float m  = S * inv;
            const float vt = Q * inv - m * m;
            const float d  = m - mu;
            var = AFWD * var + (1.0f - AFWD) * vt
                + AFWD * (1.0f - AFWD) * d * d;
            mu  = mu + (1.0f - AFWD) * d;
        }
        upto = t;

        smu[tid] = mu;
        srs[tid] = 1.0f / sqrtf(var + EPS);
        __syncthreads();                                   // D: stats broadcast ready

        // ---- Phase 4: normalize register-held chunk, NT-store (out never re-read)
        const float4 m4 = ((const float4*)smu)[cq];
        const float4 r4 = ((const float4*)srs)[cq];
        #pragma unroll
        for (int k = 0; k < F4PT; ++k) {
            nfloat4 o;
            o.x = (v[k].x - m4.x) * r4.x;
            o.y = (v[k].y - m4.y) * r4.y;
            o.z = (v[k].z - m4.z) * r4.z;
            o.w = (v[k].w - m4.w) * r4.w;
            __builtin_nontemporal_store(
                o, (nfloat4*)&out4[base + (rs + k * 4) * CQ + cq]);
        }
        // Next iteration's ls/lq and smu/srs writes are ordered after barrier A/C,
        // which every thread reaches only after finishing its stores' issue.
    }
}

// ---------------------------------------------------------------------------
// Host launcher. Workspace: accum_s[B*C] + accum_q[B*C] floats + done[B] ints.
// ---------------------------------------------------------------------------
extern "C" void kernel_launch(void* const* d_in, const int* in_sizes, int n_in,
                              void* d_out, int out_size, void* d_ws, size_t ws_size,
                              hipStream_t stream) {
    const float4* x4   = (const float4*)d_in[0];
    const float*  mu0  = (const float*)d_in[1];
    const float*  var0 = (const float*)d_in[2];
    // d_in[3] (u0), d_in[4] (v0): backward-only controls, unused in fwd.
    float4* out4 = (float4*)d_out;

    float* accum_s = (float*)d_ws;
    float* accum_q = accum_s + B * C;
    int*   done    = (int*)(accum_q + B * C);

    // Zero accumulators + done flags (harness poisons d_ws each call).
    (void)hipMemsetAsync(d_ws, 0,
                         (size_t)(2 * B * C) * sizeof(float) + B * sizeof(int),
                         stream);

    void* args[] = {(void*)&x4, (void*)&mu0, (void*)&var0,
                    (void*)&accum_s, (void*)&accum_q, (void*)&done, (void*)&out4};
    (void)hipLaunchCooperativeKernel((const void*)fused_onorm, dim3(GRID),
                                     dim3(256), args, 0, stream);
}

// Round 3
// 258.707 us; speedup vs baseline: 2.9900x; 2.9900x over previous
//
#include <hip/hip_runtime.h>
#include <math.h>

#define AFWD 0.999f
#define EPS  1e-5f

constexpr int B  = 32;
constexpr int HW = 64 * 64;      // 4096 spatial positions per sample
constexpr int C  = 256;          // channels
constexpr int CQ = C / 4;        // 64 channel-quads (float4)
constexpr int CHUNKS = 32;       // spatial chunks per sample
constexpr int RPC = HW / CHUNKS; // 128 rows per chunk

// Native vector type for __builtin_nontemporal_store (HIP float4 is a class).
typedef float nfloat4 __attribute__((ext_vector_type(4)));

// ---------------------------------------------------------------------------
// Kernel 1: per-(t,chunk) partial sums -> atomicAdd into accum_s/accum_q[t][c].
// Block 256 thr: cq = tid&63 (channel quad), rs = tid>>6 (row sub-lane).
// Wave reads 64 consecutive float4 = 1KB, fully coalesced. Regular loads so
// x is left resident in L3 (134 MB < 256 MB) for k2's re-read.
// ---------------------------------------------------------------------------
__global__ void __launch_bounds__(256)
k1_partial(const float4* __restrict__ x4,
           float* __restrict__ accum_s,
           float* __restrict__ accum_q) {
    const int blk   = blockIdx.x;
    const int t     = blk >> 5;
    const int chunk = blk & 31;
    const int tid   = threadIdx.x;
    const int cq    = tid & 63;
    const int rs    = tid >> 6;

    const long base = (long)(t * HW + chunk * RPC) * CQ;

    float4 s = make_float4(0.f, 0.f, 0.f, 0.f);
    float4 q = make_float4(0.f, 0.f, 0.f, 0.f);
    #pragma unroll 4
    for (int k = 0; k < RPC / 4; ++k) {
        const float4 v = x4[base + (long)(rs + k * 4) * CQ + cq];
        s.x += v.x; s.y += v.y; s.z += v.z; s.w += v.w;
        q.x += v.x * v.x; q.y += v.y * v.y; q.z += v.z * v.z; q.w += v.w * v.w;
    }

    __shared__ float4 ls[256];
    __shared__ float4 lq[256];
    ls[tid] = s;
    lq[tid] = q;
    __syncthreads();

    // Thread tid owns channel c = tid. Word index read = k*256 + c -> bank c%32,
    // conflict-free.
    const int c    = tid;
    const int cq2  = c >> 2;
    const int comp = c & 3;
    float ssum = 0.f, qsum = 0.f;
    #pragma unroll
    for (int k = 0; k < 4; ++k) {
        ssum += ((const float*)&ls[k * 64 + cq2])[comp];
        qsum += ((const float*)&lq[k * 64 + cq2])[comp];
    }
    atomicAdd(&accum_s[t * C + c], ssum);
    atomicAdd(&accum_q[t * C + c], qsum);
}

// ---------------------------------------------------------------------------
// Kernel 2: per-block redundant EMA scan (<=31 steps from finalized accum),
// then normalize this block's chunk. x re-read should be L3-resident (left
// there by k1); out stored NON-TEMPORALLY so the 134 MB write stream does not
// evict x from L2/L3 mid-kernel (out is never re-read).
// ---------------------------------------------------------------------------
__global__ void __launch_bounds__(256)
k2_norm(const float4* __restrict__ x4,
        const float* __restrict__ mu0,
        const float* __restrict__ var0,
        const float* __restrict__ accum_s,
        const float* __restrict__ accum_q,
        float4* __restrict__ out4) {
    const int blk   = blockIdx.x;
    const int t     = blk >> 5;
    const int chunk = blk & 31;
    const int tid   = threadIdx.x;

    // Scan for channel c = tid: carry after samples 0..t-1.
    float mu  = mu0[tid];
    float var = var0[tid];
    const float inv = 1.0f / (float)HW;
    for (int tt = 0; tt < t; ++tt) {
        const float m  = accum_s[tt * C + tid] * inv;
        const float vt = accum_q[tt * C + tid] * inv - m * m;
        const float d  = m - mu;
        var = AFWD * var + (1.0f - AFWD) * vt + AFWD * (1.0f - AFWD) * d * d;
        mu  = mu + (1.0f - AFWD) * d;
    }

    __shared__ float smu[C];
    __shared__ float srs[C];
    smu[tid] = mu;
    srs[tid] = 1.0f / sqrtf(var + EPS);
    __syncthreads();

    const int cq = tid & 63;
    const int rs = tid >> 6;
    const float4 mu4 = ((const float4*)smu)[cq];
    const float4 rs4 = ((const float4*)srs)[cq];

    const long base = (long)(t * HW + chunk * RPC) * CQ;
    #pragma unroll 4
    for (int k = 0; k < RPC / 4; ++k) {
        const long i = base + (long)(rs + k * 4) * CQ + cq;
        const float4 v = x4[i];
        nfloat4 o;
        o.x = (v.x - mu4.x) * rs4.x;
        o.y = (v.y - mu4.y) * rs4.y;
        o.z = (v.z - mu4.z) * rs4.z;
        o.w = (v.w - mu4.w) * rs4.w;
        __builtin_nontemporal_store(o, (nfloat4*)&out4[i]);
    }
}

// ---------------------------------------------------------------------------
// Host launcher. Workspace: accum_s [B*C] floats, accum_q [B*C] floats = 64KB.
// ---------------------------------------------------------------------------
extern "C" void kernel_launch(void* const* d_in, const int* in_sizes, int n_in,
                              void* d_out, int out_size, void* d_ws, size_t ws_size,
                              hipStream_t stream) {
    const float4* x4   = (const float4*)d_in[0];
    const float*  mu0  = (const float*)d_in[1];
    const float*  var0 = (const float*)d_in[2];
    // d_in[3] (u0), d_in[4] (v0): backward-only controls, unused in fwd.
    float4* out4 = (float4*)d_out;

    float* accum_s = (float*)d_ws;
    float* accum_q = accum_s + B * C;

    // Zero the atomic accumulators (harness poisons d_ws each call).
    (void)hipMemsetAsync(d_ws, 0, 2 * B * C * sizeof(float), stream);

    k1_partial<<<dim3(B * CHUNKS), 256, 0, stream>>>(x4, accum_s, accum_q);

    k2_norm<<<dim3(B * CHUNKS), 256, 0, stream>>>(x4, mu0, var0,
                                                  accum_s, accum_q, out4);
}